// Round 1
// baseline (1514.401 us; speedup 1.0000x reference)
//
#include <hip/hip_runtime.h>
#include <math.h>

#define B_  128
#define T_  2048
#define D_  128
#define M_  64
#define BT_ (B_*T_)

// ---------------------------------------------------------------------------
// K0: build Wt[k][320]  (transposed, concatenated weights)
//   n in [0,128)   -> e_w[n][k]
//   n in [128,256) -> a_w[n-128][k]
//   n in [256,320) -> MS[n-256][k]
// ---------------------------------------------------------------------------
__global__ void k_transpose(const float* __restrict__ e_w,
                            const float* __restrict__ a_w,
                            const float* __restrict__ MS,
                            float* __restrict__ Wt) {
  int k = blockIdx.x;        // 0..127
  int n = threadIdx.x;       // 0..319
  float v;
  if (n < 128)      v = e_w[n * D_ + k];
  else if (n < 256) v = a_w[(n - 128) * D_ + k];
  else              v = MS[(n - 256) * D_ + k];
  Wt[k * 320 + n] = v;
}

// ---------------------------------------------------------------------------
// K1: fused GEMM  [BT,128] x Wt[128,320] -> {e, a, w(softmax)}
// grid (5, BT/128); block 256 = 16tx x 16ty; reg tile 8 rows x 4 cols.
// All operands read through L1 (X rows broadcast across tx; Wt coalesced).
// ---------------------------------------------------------------------------
__global__ __launch_bounds__(256, 2)
void k_gemm(const float* __restrict__ q, const float* __restrict__ qa,
            const float* __restrict__ Wt, const float* __restrict__ e_b,
            const float* __restrict__ a_b, float* __restrict__ w_ws,
            float* __restrict__ e_ws, float* __restrict__ a_ws) {
  const int nb = blockIdx.x;          // col-block 0..4
  const int rb = blockIdx.y;          // row-block 0..2047
  const int tx = threadIdx.x & 15;
  const int ty = threadIdx.x >> 4;
  const int r0 = rb * 128;
  const int n0 = nb * 64;

  const float* X    = (nb == 4) ? q : qa;   // scores use q, gates use qa
  const float* xrow = X + (size_t)(r0 + ty * 8) * D_;
  const float* wcol = Wt + n0 + tx * 4;

  float acc[8][4];
#pragma unroll
  for (int i = 0; i < 8; ++i)
#pragma unroll
    for (int j = 0; j < 4; ++j) acc[i][j] = 0.f;

  float4 xa[8], xb[8], wa[4], wb[4];

  auto LOADX = [&](float4* xr, float4* wr, int kk) {
#pragma unroll
    for (int i = 0; i < 8; ++i)
      xr[i] = *(const float4*)(xrow + (size_t)i * D_ + kk);
#pragma unroll
    for (int c = 0; c < 4; ++c)
      wr[c] = *(const float4*)(wcol + (size_t)(kk + c) * 320);
  };
  auto FMA = [&](const float4* xr, const float4* wr) {
#pragma unroll
    for (int c = 0; c < 4; ++c) {
      float4 wv = wr[c];
#pragma unroll
      for (int i = 0; i < 8; ++i) {
        float xv = ((const float*)&xr[i])[c];
        acc[i][0] = fmaf(xv, wv.x, acc[i][0]);
        acc[i][1] = fmaf(xv, wv.y, acc[i][1]);
        acc[i][2] = fmaf(xv, wv.z, acc[i][2]);
        acc[i][3] = fmaf(xv, wv.w, acc[i][3]);
      }
    }
  };

  LOADX(xa, wa, 0);
  for (int kk = 0; kk < 128; kk += 8) {
    if (kk + 4 < 128) LOADX(xb, wb, kk + 4);
    FMA(xa, wa);
    if (kk + 8 < 128) LOADX(xa, wa, kk + 8);
    FMA(xb, wb);
  }

  if (nb == 4) {
    // softmax over the 64 score cols (spread across 16 tx, 4 each)
#pragma unroll
    for (int i = 0; i < 8; ++i) {
      float mx = fmaxf(fmaxf(acc[i][0], acc[i][1]), fmaxf(acc[i][2], acc[i][3]));
#pragma unroll
      for (int s = 1; s < 16; s <<= 1) mx = fmaxf(mx, __shfl_xor(mx, s));
      float e0 = expf(acc[i][0] - mx);
      float e1 = expf(acc[i][1] - mx);
      float e2 = expf(acc[i][2] - mx);
      float e3 = expf(acc[i][3] - mx);
      float sum = e0 + e1 + e2 + e3;
#pragma unroll
      for (int s = 1; s < 16; s <<= 1) sum += __shfl_xor(sum, s);
      float inv = 1.0f / sum;
      float4 o = make_float4(e0 * inv, e1 * inv, e2 * inv, e3 * inv);
      *(float4*)(w_ws + (size_t)(r0 + ty * 8 + i) * M_ + tx * 4) = o;
    }
  } else {
    const int n  = n0 + tx * 4;          // 0..255
    const bool is_e = (n < 128);
    const float* bias = is_e ? (e_b + n) : (a_b + (n - 128));
    float b0 = bias[0], b1 = bias[1], b2 = bias[2], b3 = bias[3];
    float* dst = is_e ? e_ws : a_ws;
    const int cn = n & 127;
#pragma unroll
    for (int i = 0; i < 8; ++i) {
      float x0 = acc[i][0] + b0, x1 = acc[i][1] + b1;
      float x2 = acc[i][2] + b2, x3 = acc[i][3] + b3;
      float4 o;
      if (is_e) {
        o.x = 1.f / (1.f + expf(-x0));
        o.y = 1.f / (1.f + expf(-x1));
        o.z = 1.f / (1.f + expf(-x2));
        o.w = 1.f / (1.f + expf(-x3));
      } else {
        o.x = tanhf(x0); o.y = tanhf(x1); o.z = tanhf(x2); o.w = tanhf(x3);
      }
      *(float4*)(dst + (size_t)(r0 + ty * 8 + i) * D_ + cn) = o;
    }
  }
}

// ---------------------------------------------------------------------------
// K2: sequential scan over T. 512 wgs = (b, d-slice of 32), XCD-swizzled so
// all 4 slices of a batch land on one XCD (w stream L2-shared).
// Thread = (d, m-group of 8): mem[8] in regs; read-reduce via 3x shfl_xor
// (barrier-free); ring-4 register prefetch of w/e/a hides HBM latency.
// ---------------------------------------------------------------------------
__global__ __launch_bounds__(256, 1)
void k_scan(const float* __restrict__ w_ws, const float* __restrict__ e_ws,
            const float* __restrict__ a_ws, const float* __restrict__ dy,
            float* __restrict__ out) {
  // bijective XCD swizzle: 512 = 8 * 64
  int o  = ((blockIdx.x & 7) << 6) | (blockIdx.x >> 3);
  int b  = o >> 2;
  int dq = o & 3;

  int lane = threadIdx.x & 63;
  int wv   = threadIdx.x >> 6;          // wave 0..3
  int mg   = lane & 7;                  // m-group 0..7
  int dl   = (wv << 3) | (lane >> 3);   // 0..31
  int d    = (dq << 5) + dl;
  int m0   = mg << 3;                   // 8 m per thread

  float mem[8];
#pragma unroll
  for (int j = 0; j < 8; ++j) mem[j] = dy[(size_t)(m0 + j) * D_ + d];

  const float* wp = w_ws + (size_t)b * T_ * M_ + m0;
  const float* ep = e_ws + (size_t)b * T_ * D_ + d;
  const float* ap = a_ws + (size_t)b * T_ * D_ + d;
  float*       op = out  + (size_t)b * T_ * D_ + d;

  float4 wlo[4], whi[4];
  float  ebuf[4], abuf[4];

  auto LOAD = [&](int s, int t) {
    const float* wpt = wp + (size_t)t * M_;
    wlo[s]  = *(const float4*)(wpt);
    whi[s]  = *(const float4*)(wpt + 4);
    ebuf[s] = ep[(size_t)t * D_];
    abuf[s] = ap[(size_t)t * D_];
  };
  auto STEP = [&](int s, int t) {
    float wvv[8] = {wlo[s].x, wlo[s].y, wlo[s].z, wlo[s].w,
                    whi[s].x, whi[s].y, whi[s].z, whi[s].w};
    float e = ebuf[s], a = abuf[s];
    float r = 0.f;
#pragma unroll
    for (int j = 0; j < 8; ++j) {
      r = fmaf(wvv[j], mem[j], r);
      float h = fmaf(-e, mem[j], a);       // h = a - e*mem
      mem[j]  = fmaf(wvv[j], h, mem[j]);   // mem += w*h
    }
    r += __shfl_xor(r, 1);
    r += __shfl_xor(r, 2);
    r += __shfl_xor(r, 4);
    if (mg == 0) op[(size_t)t * D_] = r;
  };

  LOAD(0, 0); LOAD(1, 1); LOAD(2, 2); LOAD(3, 3);
  for (int t = 0; t < T_; t += 4) {
#pragma unroll
    for (int s = 0; s < 4; ++s) {
      STEP(s, t + s);
      int tn = t + s + 4;
      if (tn > T_ - 1) tn = T_ - 1;        // harmless tail re-load
      LOAD(s, tn);
    }
  }
}

// ---------------------------------------------------------------------------
extern "C" void kernel_launch(void* const* d_in, const int* in_sizes, int n_in,
                              void* d_out, int out_size, void* d_ws, size_t ws_size,
                              hipStream_t stream) {
  const float* q      = (const float*)d_in[0];
  const float* qa     = (const float*)d_in[1];
  const float* MS     = (const float*)d_in[2];
  const float* dy_mem = (const float*)d_in[3];
  const float* e_w    = (const float*)d_in[4];
  const float* e_b    = (const float*)d_in[5];
  const float* a_w    = (const float*)d_in[6];
  const float* a_b    = (const float*)d_in[7];
  float* out = (float*)d_out;

  float* Wt  = (float*)d_ws;                       // 128*320
  float* wws = Wt  + (size_t)128 * 320;            // BT*64
  float* ews = wws + (size_t)BT_ * M_;             // BT*128
  float* aws = ews + (size_t)BT_ * D_;             // BT*128

  k_transpose<<<128, 320, 0, stream>>>(e_w, a_w, MS, Wt);
  k_gemm<<<dim3(5, BT_ / 128), 256, 0, stream>>>(q, qa, Wt, e_b, a_b,
                                                 wws, ews, aws);
  k_scan<<<512, 256, 0, stream>>>(wws, ews, aws, dy_mem, out);
}

// Round 2
// 998.256 us; speedup vs baseline: 1.5170x; 1.5170x over previous
//
#include <hip/hip_runtime.h>
#include <math.h>

#define B_  128
#define T_  2048
#define D_  128
#define M_  64
#define BT_ (B_*T_)
#define TC_ 64              // scan chunk timesteps
#define NC_ (T_/TC_)        // 32 chunks

// async global->LDS, 16B per lane. Dest must be wave-uniform base + lane*16.
#define GLL16(src, dst)                                                     \
  __builtin_amdgcn_global_load_lds(                                         \
      (const __attribute__((address_space(1))) void*)(src),                 \
      (__attribute__((address_space(3))) void*)(dst), 16, 0, 0)

// ---------------------------------------------------------------------------
// K0: build Wt[k][320]  (transposed, concatenated weights)
//   n in [0,128) -> e_w[n][k]; [128,256) -> a_w; [256,320) -> MS
// ---------------------------------------------------------------------------
__global__ void k_transpose(const float* __restrict__ e_w,
                            const float* __restrict__ a_w,
                            const float* __restrict__ MS,
                            float* __restrict__ Wt) {
  int k = blockIdx.x;
  int n = threadIdx.x;
  float v;
  if (n < 128)      v = e_w[n * D_ + k];
  else if (n < 256) v = a_w[(n - 128) * D_ + k];
  else              v = MS[(n - 256) * D_ + k];
  Wt[k * 320 + n] = v;
}

// ---------------------------------------------------------------------------
// K1: fused GEMM  [BT,128] x Wt[128,320] -> {e, a, w(softmax)}
// grid (5, BT/128); block 256 = 16tx x 16ty; reg tile 8 rows x 4 cols.
// W tile (128x64, 32KB) staged once in LDS; X staged per BK=32 chunk,
// double-buffered, via global_load_lds. X LDS uses a per-row k-block
// rotation (applied to the GLOBAL source, same rotation on read) to break
// the 4-way bank conflict of row-stride-128B reads.
// ---------------------------------------------------------------------------
__global__ __launch_bounds__(256, 2)
void k_gemm(const float* __restrict__ q, const float* __restrict__ qa,
            const float* __restrict__ Wt, const float* __restrict__ e_b,
            const float* __restrict__ a_b, float* __restrict__ w_ws,
            float* __restrict__ e_ws, float* __restrict__ a_ws) {
  __shared__ float Wl[128 * 64];      // 32KB, [k][64 cols]
  __shared__ float Xl[2][128 * 32];   // 2 x 16KB, [row][32 k] (k-blocks rotated)

  const int nb  = blockIdx.x;         // col-block 0..4
  const int rb  = blockIdx.y;         // row-block
  const int tid = threadIdx.x;
  const int tx  = tid & 15;
  const int ty  = tid >> 4;
  const int r0  = rb * 128;
  const int n0  = nb * 64;
  const float* X = (nb == 4) ? q : qa;

  // stage whole W tile: 8192 floats = 2048 x 16B units, 8 per thread
#pragma unroll
  for (int i = 0; i < 8; ++i) {
    int u = tid + i * 256;
    int k = u >> 4, col = (u & 15) * 4;
    GLL16(Wt + (size_t)k * 320 + n0 + col, Wl + u * 4);
  }

  auto STAGEX = [&](int buf, int k0) {
#pragma unroll
    for (int i = 0; i < 4; ++i) {
      int u   = tid + i * 256;           // 1024 units
      int row = u >> 3;
      int kb  = u & 7;
      int kbs = (kb + (row >> 3)) & 7;   // source k-block rotation
      GLL16(X + (size_t)(r0 + row) * 128 + k0 + kbs * 4, Xl[buf] + u * 4);
    }
  };

  float acc[8][4];
#pragma unroll
  for (int i = 0; i < 8; ++i)
#pragma unroll
    for (int j = 0; j < 4; ++j) acc[i][j] = 0.f;

  STAGEX(0, 0);
  __syncthreads();                      // drains W + X chunk 0

  const int rot = ty & 7;               // read-side rotation for this thread's rows
  for (int c = 0; c < 4; ++c) {
    if (c < 3) STAGEX((c + 1) & 1, (c + 1) * 32);
    const float* Xb = Xl[c & 1];
    const float* Wb = Wl + c * 32 * 64;
#pragma unroll
    for (int k4 = 0; k4 < 8; ++k4) {
      float4 wv[4];
#pragma unroll
      for (int kk = 0; kk < 4; ++kk)
        wv[kk] = *(const float4*)(Wb + (size_t)(k4 * 4 + kk) * 64 + tx * 4);
      const int ldsb = (k4 - rot) & 7;
#pragma unroll
      for (int i = 0; i < 8; ++i) {
        float4 xv = *(const float4*)(Xb + (size_t)(ty * 8 + i) * 32 + ldsb * 4);
#pragma unroll
        for (int kk = 0; kk < 4; ++kk) {
          float xk = ((const float*)&xv)[kk];
          acc[i][0] = fmaf(xk, wv[kk].x, acc[i][0]);
          acc[i][1] = fmaf(xk, wv[kk].y, acc[i][1]);
          acc[i][2] = fmaf(xk, wv[kk].z, acc[i][2]);
          acc[i][3] = fmaf(xk, wv[kk].w, acc[i][3]);
        }
      }
    }
    __syncthreads();
  }

  if (nb == 4) {
    // softmax over 64 score cols (16 tx lanes x 4 each)
#pragma unroll
    for (int i = 0; i < 8; ++i) {
      float mx = fmaxf(fmaxf(acc[i][0], acc[i][1]), fmaxf(acc[i][2], acc[i][3]));
#pragma unroll
      for (int s = 1; s < 16; s <<= 1) mx = fmaxf(mx, __shfl_xor(mx, s));
      float e0 = expf(acc[i][0] - mx);
      float e1 = expf(acc[i][1] - mx);
      float e2 = expf(acc[i][2] - mx);
      float e3 = expf(acc[i][3] - mx);
      float sum = e0 + e1 + e2 + e3;
#pragma unroll
      for (int s = 1; s < 16; s <<= 1) sum += __shfl_xor(sum, s);
      float inv = 1.0f / sum;
      float4 o = make_float4(e0 * inv, e1 * inv, e2 * inv, e3 * inv);
      *(float4*)(w_ws + (size_t)(r0 + ty * 8 + i) * M_ + tx * 4) = o;
    }
  } else {
    const int n = n0 + tx * 4;
    const bool is_e = (n < 128);
    const float* bias = is_e ? (e_b + n) : (a_b + (n - 128));
    float b0 = bias[0], b1 = bias[1], b2 = bias[2], b3 = bias[3];
    float* dst = is_e ? e_ws : a_ws;
    const int cn = n & 127;
#pragma unroll
    for (int i = 0; i < 8; ++i) {
      float x0 = acc[i][0] + b0, x1 = acc[i][1] + b1;
      float x2 = acc[i][2] + b2, x3 = acc[i][3] + b3;
      float4 o;
      if (is_e) {
        o.x = 1.f / (1.f + expf(-x0));
        o.y = 1.f / (1.f + expf(-x1));
        o.z = 1.f / (1.f + expf(-x2));
        o.w = 1.f / (1.f + expf(-x3));
      } else {
        o.x = tanhf(x0); o.y = tanhf(x1); o.z = tanhf(x2); o.w = tanhf(x3);
      }
      *(float4*)(dst + (size_t)(r0 + ty * 8 + i) * D_ + cn) = o;
    }
  }
}

// ---------------------------------------------------------------------------
// K2: sequential scan over T. 512 wgs = (b, d-slice of 32), XCD-swizzled.
// Thread = (d, m-group of 8). w/e/a staged in LDS per 64-t chunk,
// double-buffered, bulk async global_load_lds (latency hidden under the
// previous chunk's compute). Per-step memory = ds_read only.
// ---------------------------------------------------------------------------
__global__ __launch_bounds__(256, 1)
void k_scan(const float* __restrict__ w_ws, const float* __restrict__ e_ws,
            const float* __restrict__ a_ws, const float* __restrict__ dy,
            float* __restrict__ out) {
  // per chunk: w TC*64 | e TC*32 | a TC*32  = 8192 floats = 32KB
  __shared__ float lds[2][TC_ * 128];

  int o  = ((blockIdx.x & 7) << 6) | (blockIdx.x >> 3);  // bijective XCD swizzle
  int b  = o >> 2;
  int dq = o & 3;

  int tid  = threadIdx.x;
  int lane = tid & 63;
  int mg   = lane & 7;                  // m-group 0..7
  int dl   = ((tid >> 6) << 3) | (lane >> 3);  // 0..31
  int d    = (dq << 5) + dl;
  int m0   = mg << 3;

  float mem[8];
#pragma unroll
  for (int j = 0; j < 8; ++j) mem[j] = dy[(size_t)(m0 + j) * D_ + d];

  const float* wbase = w_ws + (size_t)b * T_ * M_;
  const float* ebase = e_ws + (size_t)b * T_ * D_ + dq * 32;
  const float* abase = a_ws + (size_t)b * T_ * D_ + dq * 32;
  float*       op    = out  + (size_t)b * T_ * D_ + d;

  auto STAGE = [&](int buf, int c) {
    int t0 = c * TC_;
    float* L = lds[buf];
    // w: TC*64 floats contiguous in global -> 1024 units, 4/thread
#pragma unroll
    for (int i = 0; i < 4; ++i) {
      int u = tid + i * 256;
      GLL16(wbase + (size_t)t0 * 64 + u * 4, L + u * 4);
    }
    // e: TC rows of 32 floats -> 512 units, 2/thread
#pragma unroll
    for (int i = 0; i < 2; ++i) {
      int u  = tid + i * 256;
      int tt = u >> 3, inner = (u & 7) * 4;
      GLL16(ebase + (size_t)(t0 + tt) * D_ + inner, L + TC_ * 64 + u * 4);
    }
    // a: same
#pragma unroll
    for (int i = 0; i < 2; ++i) {
      int u  = tid + i * 256;
      int tt = u >> 3, inner = (u & 7) * 4;
      GLL16(abase + (size_t)(t0 + tt) * D_ + inner, L + TC_ * 96 + u * 4);
    }
  };

  STAGE(0, 0);
  __syncthreads();

  for (int c = 0; c < NC_; ++c) {
    if (c + 1 < NC_) STAGE((c + 1) & 1, c + 1);
    const float* L  = lds[c & 1];
    const float* Lw = L;
    const float* Le = L + TC_ * 64;
    const float* La = L + TC_ * 96;
    const int t0 = c * TC_;
#pragma unroll 8
    for (int tt = 0; tt < TC_; ++tt) {
      float4 wlo = *(const float4*)(Lw + tt * 64 + m0);
      float4 whi = *(const float4*)(Lw + tt * 64 + m0 + 4);
      float  e   = Le[tt * 32 + dl];
      float  a   = La[tt * 32 + dl];
      float wvv[8] = {wlo.x, wlo.y, wlo.z, wlo.w, whi.x, whi.y, whi.z, whi.w};
      float r = 0.f;
#pragma unroll
      for (int j = 0; j < 8; ++j) {
        r = fmaf(wvv[j], mem[j], r);          // read uses OLD mem
        float h = fmaf(-e, mem[j], a);        // h = a - e*mem
        mem[j]  = fmaf(wvv[j], h, mem[j]);    // mem += w*h
      }
      r += __shfl_xor(r, 1);
      r += __shfl_xor(r, 2);
      r += __shfl_xor(r, 4);
      if (mg == 0) op[(size_t)(t0 + tt) * D_] = r;
    }
    __syncthreads();
  }
}

// ---------------------------------------------------------------------------
extern "C" void kernel_launch(void* const* d_in, const int* in_sizes, int n_in,
                              void* d_out, int out_size, void* d_ws, size_t ws_size,
                              hipStream_t stream) {
  const float* q      = (const float*)d_in[0];
  const float* qa     = (const float*)d_in[1];
  const float* MS     = (const float*)d_in[2];
  const float* dy_mem = (const float*)d_in[3];
  const float* e_w    = (const float*)d_in[4];
  const float* e_b    = (const float*)d_in[5];
  const float* a_w    = (const float*)d_in[6];
  const float* a_b    = (const float*)d_in[7];
  float* out = (float*)d_out;

  float* Wt  = (float*)d_ws;                       // 128*320
  float* wws = Wt  + (size_t)128 * 320;            // BT*64
  float* ews = wws + (size_t)BT_ * M_;             // BT*128
  float* aws = ews + (size_t)BT_ * D_;             // BT*128

  k_transpose<<<128, 320, 0, stream>>>(e_w, a_w, MS, Wt);
  k_gemm<<<dim3(5, BT_ / 128), 256, 0, stream>>>(q, qa, Wt, e_b, a_b,
                                                 wws, ews, aws);
  k_scan<<<512, 256, 0, stream>>>(wws, ews, aws, dy_mem, out);
}